// Round 13
// baseline (140.968 us; speedup 1.0000x reference)
//
#include <hip/hip_runtime.h>

#define FEATS 64
#define PSZ   64            // nodes per partition (= one gather block)
#define MAXP  1280          // >= ceil(75000/64) = 1172
#define PSCH  4688          // edges per chunk; 4688*256 >= 1.2M
#define SPT   512           // gather threads per block
#define SPTP  1024          // prep threads per block (16 waves)
#define PEPT  5             // ceil(PSCH/SPTP)
#define NCH   256           // sort chunks
#define CAPP  2560          // padded LDS bucket capacity (mean ~1250 w/ pad8)

typedef __attribute__((ext_vector_type(8))) short short8;   // 8 bf16 = 4 VGPRs
typedef __attribute__((ext_vector_type(4))) float floatx4;  // MFMA accumulator

static __device__ __forceinline__ unsigned short f2bf(float f) {
    const unsigned int u = __float_as_uint(f);
    return (unsigned short)((u + 0x7FFFu + ((u >> 16) & 1u)) >> 16);
}
static __device__ __forceinline__ float bflo(unsigned int u) {
    return __uint_as_float(u << 16);            // low bf16 -> fp32
}
static __device__ __forceinline__ float bfhi(unsigned int u) {
    return __uint_as_float(u & 0xFFFF0000u);    // high bf16 -> fp32
}

// ---------------------------------------------------------------------------
// K1 prep_fused (R11 verbatim): heterogeneous grid, 1024-thread blocks.
//  blocks [0,nbs): SORT role. Preloaded dst -> LDS-atomic rank -> preloaded
//    src overlapping the 16-wave shuffle scan -> LDS placement -> coalesced
//    slab write + chunk-major runoffC[chunk][p] contiguous row write.
//  blocks [nbs,...): CONVERT role. Fs16 = bf16(feature*rsqrt(deg)).
// prk = p | r<<11 | dl<<24 (r < 4688: 13 bits). Record = src | dl<<17.
// ---------------------------------------------------------------------------
__global__ __launch_bounds__(SPTP) void prep_fused(
        const float* __restrict__ degree,
        const float* __restrict__ feature,
        const float* __restrict__ Wm,
        const int* __restrict__ src,
        const int* __restrict__ dst,
        unsigned short* __restrict__ Fs16,
        unsigned short* __restrict__ WtB,
        int* __restrict__ slab,
        unsigned short* __restrict__ runoffC,
        int n_nodes, int n_edges, int np, int nbs) {
    __shared__ int cnt[MAXP];        // per-partition count, then exclusive loc
    __shared__ int swt[16];          // per-wave scan totals
    __shared__ __align__(16) int sval[PSCH];
    const int tid = threadIdx.x;
    const int lane = tid & 63;
    const int wv = tid >> 6;
    const int b = blockIdx.x;

    if (b >= nbs) {
        // ---- CONVERT role: pure streaming, one 8-elem chunk per thread ----
        const int idx = (b - nbs) * SPTP + tid;
        const int total = n_nodes * 8;
        if (idx < total) {
            const float w = rsqrtf(degree[idx >> 3]);
            const float4* f4 = (const float4*)feature;
            const float4 fa = f4[idx * 2];
            const float4 fb = f4[idx * 2 + 1];
            uint4 o;
            o.x = (unsigned int)f2bf(fa.x * w) | ((unsigned int)f2bf(fa.y * w) << 16);
            o.y = (unsigned int)f2bf(fa.z * w) | ((unsigned int)f2bf(fa.w * w) << 16);
            o.z = (unsigned int)f2bf(fb.x * w) | ((unsigned int)f2bf(fb.y * w) << 16);
            o.w = (unsigned int)f2bf(fb.z * w) | ((unsigned int)f2bf(fb.w * w) << 16);
            ((uint4*)Fs16)[idx] = o;
        }
        if (b == nbs) {
            if (tid < FEATS) Fs16[(size_t)n_nodes * FEATS + tid] = 0;  // zero row
            for (int i = tid; i < FEATS * FEATS; i += SPTP) {
                const int k = i >> 6, n = i & 63;
                WtB[n * FEATS + k] = f2bf(Wm[i]);       // W^T in bf16
            }
        }
        return;
    }

    // ---- SORT role ----
    for (int i = tid; i < np; i += SPTP) cnt[i] = 0;
    __syncthreads();

    const int estart = b * PSCH;
    const int eend = min(estart + PSCH, n_edges);
    const int mb = eend - estart;

    int dv[PEPT];
#pragma unroll
    for (int k = 0; k < PEPT; ++k) {
        const int e = estart + tid + k * SPTP;
        dv[k] = (e < eend) ? dst[e] : -1;
    }
    int prk[PEPT];
#pragma unroll
    for (int k = 0; k < PEPT; ++k) {
        prk[k] = 0;
        if (dv[k] >= 0) {
            const int d = dv[k];
            const int p = d >> 6;                      // 11 bits
            const int r = atomicAdd(&cnt[p], 1);       // LDS atomic (native int)
            prk[k] = p | (r << 11) | ((d & 63) << 24); // r < 4688 (13 bits)
        }
    }
    int sv[PEPT];
#pragma unroll
    for (int k = 0; k < PEPT; ++k) {
        const int e = estart + tid + k * SPTP;
        sv[k] = (e < eend) ? src[e] : 0;
    }
    __syncthreads();

    // exclusive scan of cnt[0..np): 2/thread, wave shuffle + cross-wave
    int my[2];
    int psum = 0;
    const int p0 = tid * 2;
#pragma unroll
    for (int j = 0; j < 2; ++j) {
        const int p = p0 + j;
        my[j] = psum;
        if (p < np) psum += cnt[p];
    }
    int x = psum;
#pragma unroll
    for (int off = 1; off < 64; off <<= 1) {
        const int v = __shfl_up(x, off);
        if (lane >= off) x += v;
    }
    if (lane == 63) swt[wv] = x;
    __syncthreads();
    int wbase = 0;
#pragma unroll
    for (int w = 0; w < 16; ++w) if (w < wv) wbase += swt[w];
    const int tbase = wbase + (x - psum);
#pragma unroll
    for (int j = 0; j < 2; ++j) {
        const int p = p0 + j;
        if (p < np) cnt[p] = tbase + my[j];            // cnt becomes loc
    }
    __syncthreads();

#pragma unroll
    for (int k = 0; k < PEPT; ++k) {
        if (dv[k] >= 0) {
            const int pr = prk[k];
            const int p = pr & 2047;
            const int r = (pr >> 11) & 8191;
            const int dl = (pr >> 24) & 63;
            sval[cnt[p] + r] = (sv[k] & 0x1FFFF) | (dl << 17);
        }
    }
    __syncthreads();

    int* so = slab + estart;
    const int m4 = mb >> 2;                            // estart*4B is 16B-aligned
    int4* so4 = (int4*)so;
    const int4* sv4 = (const int4*)sval;
    for (int i = tid; i < m4; i += SPTP) so4[i] = sv4[i];
    for (int i = (m4 << 2) + tid; i < mb; i += SPTP) so[i] = sval[i];
    // chunk-major run-offset row: contiguous, coalesced, no cross-XCD sharing
    unsigned short* ro = runoffC + (size_t)b * (np + 1);
    for (int i = tid; i <= np; i += SPTP)
        ro[i] = (unsigned short)((i < np) ? cnt[i] : mb);
}

// ---------------------------------------------------------------------------
// K2 gather_apply15 (R11 + non-temporal loads): block = partition
//  (XCD-chunk-swizzled), 512 threads. The two random read streams with ~0%
//  L1 hit rate (Fs16 row gather; slab segment reads) use
//  __builtin_nontemporal_load (nt policy): no L1 allocation -> no L1
//  pollution and no L1 miss-tracking occupancy (MSHR theory, R12 analysis).
//  (a) per-node 8-aligned bucket offsets (wave-0 shuffle scan),
//  (b) bucket from contiguous runoffC rows + 256 slab runs (4 thr/run),
//  (c) uint2 gather: 16 lanes per 128-B row, 4 edges per wave-load,
//      8 edges/iter via 2 loads, unroll 4 => 8 line-fetches in flight;
//      fold via lane^16, lane^32 shuffles,
//  (d) MFMA epilogue split across 8 waves: 1 m-tile x 2 n-tiles each.
// ---------------------------------------------------------------------------
__global__ __launch_bounds__(512, 8) void gather_apply15(
        const int* __restrict__ slab,
        const unsigned short* __restrict__ runoffC,
        const float* __restrict__ degree,
        const unsigned short* __restrict__ Fs16,
        const unsigned short* __restrict__ WtB,
        const float* __restrict__ bias,
        float* __restrict__ out,
        int n_nodes, int np, int nbs) {
    __shared__ __align__(16) int ledges[CAPP];                // 10 KB
    __shared__ __align__(16) unsigned short saggb[PSZ * 72];  // 9.2 KB bf16 A-tile
    __shared__ int boffA[PSZ + 1];
    __shared__ int bcur[PSZ];
    __shared__ float swinv[PSZ];

    const int tid = threadIdx.x;
    const int lane = tid & 63;
    const int wv = tid >> 6;

    // bijective XCD-chunked swizzle (8 XCDs): consecutive p on same XCD
    int p;
    {
        const int bid = blockIdx.x;
        const int q = np >> 3, r = np & 7;
        const int xcd = bid & 7, idx = bid >> 3;
        p = ((xcd < r) ? xcd * (q + 1) : r * (q + 1) + (xcd - r) * q) + idx;
    }
    const int n0 = p * PSZ;
    const int nn = min(PSZ, n_nodes - n0);

    if (tid < PSZ) bcur[tid] = 0;
    if (wv == 0) {   // wave-0: swinv + shuffle scan of 8-padded counts
        const float dg = (lane < nn) ? degree[n0 + lane] : 1.0f;
        swinv[lane] = rsqrtf(dg);
        const int c = (lane < nn) ? ((int)(dg + 0.5f) - 1) : 0;
        const int cp = (c + 7) & ~7;
        int x = cp;
#pragma unroll
        for (int off = 1; off < 64; off <<= 1) {
            const int v = __shfl_up(x, off);
            if (lane >= off) x += v;
        }
        if (lane == 0) boffA[0] = 0;
        boffA[lane + 1] = x;
    }
    __syncthreads();
    const int mpad = boffA[PSZ];

    if (mpad <= CAPP) {
        // (b) prefill pad slots with zero-row index, then bucket (4 thr/run)
        for (int i = tid; i < mpad; i += SPT) ledges[i] = n_nodes;
        __syncthreads();
        for (int t = tid; t < nbs * 4; t += SPT) {
            const int rr = t >> 2, sub = t & 3;
            const unsigned short* ro = runoffC + (size_t)rr * (np + 1);
            const int st = ro[p];
            const int en = ro[p + 1];
            const int* g = slab + (size_t)rr * PSCH;
            for (int q = st + sub; q < en; q += 4) {
                const int rec = __builtin_nontemporal_load(g + q);
                const int dl = (rec >> 17) & 63;
                const int pos = boffA[dl] + atomicAdd(&bcur[dl], 1);
                if (pos < mpad) ledges[pos] = rec & 0x1FFFF;
            }
        }
        __syncthreads();

        // (c) gather: 8 edges/iter, 2 x 8B nt-loads, unroll 4
        const int q4 = lane >> 4;                  // quarter: edge within group
        const int c16 = lane & 15;                 // 4 cols per lane
        const unsigned long long* FsLL = (const unsigned long long*)Fs16;
        for (int n = wv; n < PSZ; n += 8) {
            const int st = boffA[n];
            const int en8 = boffA[n + 1];
            float a0 = 0.f, a1 = 0.f, a2 = 0.f, a3 = 0.f;
            float c0 = 0.f, c1 = 0.f, c2 = 0.f, c3 = 0.f;
#pragma unroll 4
            for (int j = st; j < en8; j += 8) {
                const int r0 = ledges[j + q4];
                const int r1 = ledges[j + 4 + q4];
                const unsigned long long w0 =
                    __builtin_nontemporal_load(FsLL + ((size_t)r0 << 4) + c16);
                const unsigned long long w1 =
                    __builtin_nontemporal_load(FsLL + ((size_t)r1 << 4) + c16);
                a0 += bflo((unsigned int)w0); a1 += bfhi((unsigned int)w0);
                a2 += bflo((unsigned int)(w0 >> 32)); a3 += bfhi((unsigned int)(w0 >> 32));
                c0 += bflo((unsigned int)w1); c1 += bfhi((unsigned int)w1);
                c2 += bflo((unsigned int)(w1 >> 32)); c3 += bfhi((unsigned int)(w1 >> 32));
            }
            float v0 = a0 + c0, v1 = a1 + c1, v2 = a2 + c2, v3 = a3 + c3;
            v0 += __shfl(v0, lane ^ 16); v0 += __shfl(v0, lane ^ 32);
            v1 += __shfl(v1, lane ^ 16); v1 += __shfl(v1, lane ^ 32);
            v2 += __shfl(v2, lane ^ 16); v2 += __shfl(v2, lane ^ 32);
            v3 += __shfl(v3, lane ^ 16); v3 += __shfl(v3, lane ^ 32);
            if (q4 == 0) {   // lanes 0-15 hold cols c16*4 .. c16*4+3
                const unsigned int pk0 =
                    (unsigned int)f2bf(v0) | ((unsigned int)f2bf(v1) << 16);
                const unsigned int pk1 =
                    (unsigned int)f2bf(v2) | ((unsigned int)f2bf(v3) << 16);
                uint2* dp = (uint2*)(saggb + n * 72 + c16 * 4);
                *dp = make_uint2(pk0, pk1);
            }
        }
    } else {
        // statistically-unreachable overflow: per-node scan of all runs
        __syncthreads();
        __syncthreads();
        for (int n = wv; n < PSZ; n += 8) {
            float acc = 0.f;
            for (int c = 0; c < nbs; ++c) {
                const unsigned short* ro = runoffC + (size_t)c * (np + 1);
                const int st = ro[p];
                const int en = ro[p + 1];
                const int* g = slab + (size_t)c * PSCH;
                for (int i = st; i < en; ++i) {
                    const int rec = g[i];
                    if (((rec >> 17) & 63) == n) {
                        const unsigned int us =
                            Fs16[((size_t)(rec & 0x1FFFF) << 6) + lane];
                        acc += __uint_as_float(us << 16);
                    }
                }
            }
            saggb[n * 72 + lane] = f2bf(acc);
        }
    }
    __syncthreads();

    // (d) 64x64x64 GEMM over 8 waves: wave wv -> m-tile wv>>1, n-tiles (wv&1)*2+{0,1}
    const int col = lane & 15;
    const int quad = lane >> 4;
    const int mt = wv >> 1;
    const int nh = (wv & 1) << 1;
    floatx4 acc[2] = {};
#pragma unroll
    for (int kt = 0; kt < 2; ++kt) {
        const short8 af = *(const short8*)(saggb + (mt * 16 + col) * 72 + kt * 32 + quad * 8);
#pragma unroll
        for (int t = 0; t < 2; ++t) {
            const int nt = nh + t;
            const short8 bf = *(const short8*)((const short*)WtB + (nt * 16 + col) * FEATS + kt * 32 + quad * 8);
            acc[t] = __builtin_amdgcn_mfma_f32_16x16x32_bf16(af, bf, acc[t], 0, 0, 0);
        }
    }
#pragma unroll
    for (int t = 0; t < 2; ++t) {
        const int nt = nh + t;
        const float bv = bias[nt * 16 + col];
#pragma unroll
        for (int r = 0; r < 4; ++r) {
            const int row = mt * 16 + quad * 4 + r;      // D: col=lane&15, row=quad*4+reg
            if (row < nn)
                out[(size_t)(n0 + row) * FEATS + nt * 16 + col] = swinv[row] * acc[t][r] + bv;
        }
    }
}

static inline size_t align256(size_t x) { return (x + 255) & ~(size_t)255; }

extern "C" void kernel_launch(void* const* d_in, const int* in_sizes, int n_in,
                              void* d_out, int out_size, void* d_ws, size_t ws_size,
                              hipStream_t stream) {
    const float* feature = (const float*)d_in[0];
    const float* degree  = (const float*)d_in[1];
    const int*   src     = (const int*)d_in[2];
    const int*   dst     = (const int*)d_in[3];
    const float* Wm      = (const float*)d_in[4];
    const float* bias    = (const float*)d_in[5];
    float* out = (float*)d_out;

    const int n_nodes = in_sizes[1];
    const int n_edges = in_sizes[2];
    const int np = (n_nodes + PSZ - 1) / PSZ;           // 1172
    const int nbs = NCH;                                // 256 sort chunks
    const int ncv = (n_nodes * 8 + SPTP - 1) / SPTP;    // 586 convert blocks

    // workspace (~15.3 MB), every byte read is rewritten each launch
    char* ws = (char*)d_ws;
    unsigned short* Fs16 = (unsigned short*)ws; ws += align256(((size_t)n_nodes + 1) * FEATS * 2);
    unsigned short* WtB  = (unsigned short*)ws; ws += align256((size_t)FEATS * FEATS * 2);
    int* slab = (int*)ws;                       ws += align256((size_t)NCH * PSCH * 4);
    unsigned short* runoffC = (unsigned short*)ws; ws += align256((size_t)NCH * (np + 1) * 2);

    prep_fused<<<nbs + ncv, SPTP, 0, stream>>>(degree, feature, Wm, src, dst,
                                               Fs16, WtB, slab, runoffC,
                                               n_nodes, n_edges, np, nbs);
    gather_apply15<<<np, SPT, 0, stream>>>(slab, runoffC, degree, Fs16, WtB, bias, out,
                                           n_nodes, np, nbs);
}

// Round 14
// 123.123 us; speedup vs baseline: 1.1449x; 1.1449x over previous
//
#include <hip/hip_runtime.h>

#define FEATS 64
#define PSZ   64            // nodes per partition (= one gather block)
#define MAXP  1280          // >= ceil(75000/64) = 1172
#define PSCH  4688          // edges per chunk; 4688*256 >= 1.2M
#define SPT   512           // gather threads per block
#define SPTP  1024          // prep threads per block (16 waves)
#define PEPT  5             // ceil(PSCH/SPTP)
#define NCH   256           // sort chunks
#define CAPP  2560          // padded LDS bucket capacity (mean ~1250 w/ pad8)

typedef __attribute__((ext_vector_type(8))) short short8;   // 8 bf16 = 4 VGPRs
typedef __attribute__((ext_vector_type(4))) float floatx4;  // MFMA accumulator

static __device__ __forceinline__ unsigned short f2bf(float f) {
    const unsigned int u = __float_as_uint(f);
    return (unsigned short)((u + 0x7FFFu + ((u >> 16) & 1u)) >> 16);
}
static __device__ __forceinline__ float bflo(unsigned int u) {
    return __uint_as_float(u << 16);            // low bf16 -> fp32
}
static __device__ __forceinline__ float bfhi(unsigned int u) {
    return __uint_as_float(u & 0xFFFF0000u);    // high bf16 -> fp32
}

// ---------------------------------------------------------------------------
// K1 prep_fused (R11 verbatim): heterogeneous grid, 1024-thread blocks.
//  blocks [0,nbs): SORT role. Preloaded dst -> LDS-atomic rank -> preloaded
//    src overlapping the 16-wave shuffle scan -> LDS placement -> coalesced
//    slab write + chunk-major runoffC[chunk][p] contiguous row write.
//  blocks [nbs,...): CONVERT role. Fs16 = bf16(feature*rsqrt(deg)).
// prk = p | r<<11 | dl<<24 (r < 4688: 13 bits). Record = src | dl<<17.
// ---------------------------------------------------------------------------
__global__ __launch_bounds__(SPTP) void prep_fused(
        const float* __restrict__ degree,
        const float* __restrict__ feature,
        const float* __restrict__ Wm,
        const int* __restrict__ src,
        const int* __restrict__ dst,
        unsigned short* __restrict__ Fs16,
        unsigned short* __restrict__ WtB,
        int* __restrict__ slab,
        unsigned short* __restrict__ runoffC,
        int n_nodes, int n_edges, int np, int nbs) {
    __shared__ int cnt[MAXP];        // per-partition count, then exclusive loc
    __shared__ int swt[16];          // per-wave scan totals
    __shared__ __align__(16) int sval[PSCH];
    const int tid = threadIdx.x;
    const int lane = tid & 63;
    const int wv = tid >> 6;
    const int b = blockIdx.x;

    if (b >= nbs) {
        // ---- CONVERT role: pure streaming, one 8-elem chunk per thread ----
        const int idx = (b - nbs) * SPTP + tid;
        const int total = n_nodes * 8;
        if (idx < total) {
            const float w = rsqrtf(degree[idx >> 3]);
            const float4* f4 = (const float4*)feature;
            const float4 fa = f4[idx * 2];
            const float4 fb = f4[idx * 2 + 1];
            uint4 o;
            o.x = (unsigned int)f2bf(fa.x * w) | ((unsigned int)f2bf(fa.y * w) << 16);
            o.y = (unsigned int)f2bf(fa.z * w) | ((unsigned int)f2bf(fa.w * w) << 16);
            o.z = (unsigned int)f2bf(fb.x * w) | ((unsigned int)f2bf(fb.y * w) << 16);
            o.w = (unsigned int)f2bf(fb.z * w) | ((unsigned int)f2bf(fb.w * w) << 16);
            ((uint4*)Fs16)[idx] = o;
        }
        if (b == nbs) {
            if (tid < FEATS) Fs16[(size_t)n_nodes * FEATS + tid] = 0;  // zero row
            for (int i = tid; i < FEATS * FEATS; i += SPTP) {
                const int k = i >> 6, n = i & 63;
                WtB[n * FEATS + k] = f2bf(Wm[i]);       // W^T in bf16
            }
        }
        return;
    }

    // ---- SORT role ----
    for (int i = tid; i < np; i += SPTP) cnt[i] = 0;
    __syncthreads();

    const int estart = b * PSCH;
    const int eend = min(estart + PSCH, n_edges);
    const int mb = eend - estart;

    int dv[PEPT];
#pragma unroll
    for (int k = 0; k < PEPT; ++k) {
        const int e = estart + tid + k * SPTP;
        dv[k] = (e < eend) ? dst[e] : -1;
    }
    int prk[PEPT];
#pragma unroll
    for (int k = 0; k < PEPT; ++k) {
        prk[k] = 0;
        if (dv[k] >= 0) {
            const int d = dv[k];
            const int p = d >> 6;                      // 11 bits
            const int r = atomicAdd(&cnt[p], 1);       // LDS atomic (native int)
            prk[k] = p | (r << 11) | ((d & 63) << 24); // r < 4688 (13 bits)
        }
    }
    int sv[PEPT];
#pragma unroll
    for (int k = 0; k < PEPT; ++k) {
        const int e = estart + tid + k * SPTP;
        sv[k] = (e < eend) ? src[e] : 0;
    }
    __syncthreads();

    // exclusive scan of cnt[0..np): 2/thread, wave shuffle + cross-wave
    int my[2];
    int psum = 0;
    const int p0 = tid * 2;
#pragma unroll
    for (int j = 0; j < 2; ++j) {
        const int p = p0 + j;
        my[j] = psum;
        if (p < np) psum += cnt[p];
    }
    int x = psum;
#pragma unroll
    for (int off = 1; off < 64; off <<= 1) {
        const int v = __shfl_up(x, off);
        if (lane >= off) x += v;
    }
    if (lane == 63) swt[wv] = x;
    __syncthreads();
    int wbase = 0;
#pragma unroll
    for (int w = 0; w < 16; ++w) if (w < wv) wbase += swt[w];
    const int tbase = wbase + (x - psum);
#pragma unroll
    for (int j = 0; j < 2; ++j) {
        const int p = p0 + j;
        if (p < np) cnt[p] = tbase + my[j];            // cnt becomes loc
    }
    __syncthreads();

#pragma unroll
    for (int k = 0; k < PEPT; ++k) {
        if (dv[k] >= 0) {
            const int pr = prk[k];
            const int p = pr & 2047;
            const int r = (pr >> 11) & 8191;
            const int dl = (pr >> 24) & 63;
            sval[cnt[p] + r] = (sv[k] & 0x1FFFF) | (dl << 17);
        }
    }
    __syncthreads();

    int* so = slab + estart;
    const int m4 = mb >> 2;                            // estart*4B is 16B-aligned
    int4* so4 = (int4*)so;
    const int4* sv4 = (const int4*)sval;
    for (int i = tid; i < m4; i += SPTP) so4[i] = sv4[i];
    for (int i = (m4 << 2) + tid; i < mb; i += SPTP) so[i] = sval[i];
    // chunk-major run-offset row: contiguous, coalesced, no cross-XCD sharing
    unsigned short* ro = runoffC + (size_t)b * (np + 1);
    for (int i = tid; i <= np; i += SPTP)
        ro[i] = (unsigned short)((i < np) ? cnt[i] : mb);
}

// ---------------------------------------------------------------------------
// K2 gather_apply16 (R11 + dual-node interleaved gather): block = partition
//  (XCD-chunk-swizzled), 512 threads.
//  (a) per-node 8-aligned bucket offsets (wave-0 shuffle scan),
//  (b) bucket from contiguous runoffC rows + 256 slab runs (4 thr/run),
//  (c) DUAL-NODE gather: each wave runs TWO buckets' streams interleaved —
//      per step: 2 loads for node A + 2 loads for node B issued before
//      either is consumed => 4 independent line-fetches in flight at every
//      step, independent of the ~2-trip bucket loops (mean bucket = 16
//      edges) that defeated unroll-based MLP. Branch conds are wave-uniform.
//  (d) MFMA epilogue split across 8 waves: 1 m-tile x 2 n-tiles each.
// ---------------------------------------------------------------------------
__global__ __launch_bounds__(512, 8) void gather_apply16(
        const int* __restrict__ slab,
        const unsigned short* __restrict__ runoffC,
        const float* __restrict__ degree,
        const unsigned short* __restrict__ Fs16,
        const unsigned short* __restrict__ WtB,
        const float* __restrict__ bias,
        float* __restrict__ out,
        int n_nodes, int np, int nbs) {
    __shared__ __align__(16) int ledges[CAPP];                // 10 KB
    __shared__ __align__(16) unsigned short saggb[PSZ * 72];  // 9.2 KB bf16 A-tile
    __shared__ int boffA[PSZ + 1];
    __shared__ int bcur[PSZ];
    __shared__ float swinv[PSZ];

    const int tid = threadIdx.x;
    const int lane = tid & 63;
    const int wv = tid >> 6;

    // bijective XCD-chunked swizzle (8 XCDs): consecutive p on same XCD
    int p;
    {
        const int bid = blockIdx.x;
        const int q = np >> 3, r = np & 7;
        const int xcd = bid & 7, idx = bid >> 3;
        p = ((xcd < r) ? xcd * (q + 1) : r * (q + 1) + (xcd - r) * q) + idx;
    }
    const int n0 = p * PSZ;
    const int nn = min(PSZ, n_nodes - n0);

    if (tid < PSZ) bcur[tid] = 0;
    if (wv == 0) {   // wave-0: swinv + shuffle scan of 8-padded counts
        const float dg = (lane < nn) ? degree[n0 + lane] : 1.0f;
        swinv[lane] = rsqrtf(dg);
        const int c = (lane < nn) ? ((int)(dg + 0.5f) - 1) : 0;
        const int cp = (c + 7) & ~7;
        int x = cp;
#pragma unroll
        for (int off = 1; off < 64; off <<= 1) {
            const int v = __shfl_up(x, off);
            if (lane >= off) x += v;
        }
        if (lane == 0) boffA[0] = 0;
        boffA[lane + 1] = x;
    }
    __syncthreads();
    const int mpad = boffA[PSZ];

    if (mpad <= CAPP) {
        // (b) prefill pad slots with zero-row index, then bucket (4 thr/run)
        for (int i = tid; i < mpad; i += SPT) ledges[i] = n_nodes;
        __syncthreads();
        for (int t = tid; t < nbs * 4; t += SPT) {
            const int rr = t >> 2, sub = t & 3;
            const unsigned short* ro = runoffC + (size_t)rr * (np + 1);
            const int st = ro[p];
            const int en = ro[p + 1];
            const int* g = slab + (size_t)rr * PSCH;
            for (int q = st + sub; q < en; q += 4) {
                const int rec = g[q];
                const int dl = (rec >> 17) & 63;
                const int pos = boffA[dl] + atomicAdd(&bcur[dl], 1);
                if (pos < mpad) ledges[pos] = rec & 0x1FFFF;
            }
        }
        __syncthreads();

        // (c) dual-node interleaved gather
        const int q4 = lane >> 4;                  // quarter: edge within group
        const int c16 = lane & 15;                 // 4 cols per lane
        const uint2* FsU2 = (const uint2*)Fs16;    // 16 uint2 per 128B row
        for (int pr = wv; pr < 32; pr += 8) {
            const int nA = pr * 2, nB = nA + 1;
            int ja = boffA[nA];
            const int ea = boffA[nA + 1];
            int jb = boffA[nB];
            const int eb = boffA[nB + 1];
            float a0 = 0.f, a1 = 0.f, a2 = 0.f, a3 = 0.f;
            float b0 = 0.f, b1 = 0.f, b2 = 0.f, b3 = 0.f;
            while (ja < ea || jb < eb) {           // wave-uniform conditions
                uint2 u0a = make_uint2(0u, 0u), u1a = make_uint2(0u, 0u);
                uint2 u0b = make_uint2(0u, 0u), u1b = make_uint2(0u, 0u);
                const bool da = ja < ea;
                const bool db = jb < eb;
                if (da) {                           // issue stream-A loads
                    const int r0 = ledges[ja + q4];
                    const int r1 = ledges[ja + 4 + q4];
                    u0a = FsU2[((size_t)r0 << 4) + c16];
                    u1a = FsU2[((size_t)r1 << 4) + c16];
                }
                if (db) {                           // issue stream-B loads
                    const int r0 = ledges[jb + q4];
                    const int r1 = ledges[jb + 4 + q4];
                    u0b = FsU2[((size_t)r0 << 4) + c16];
                    u1b = FsU2[((size_t)r1 << 4) + c16];
                }
                a0 += bflo(u0a.x) + bflo(u1a.x);
                a1 += bfhi(u0a.x) + bfhi(u1a.x);
                a2 += bflo(u0a.y) + bflo(u1a.y);
                a3 += bfhi(u0a.y) + bfhi(u1a.y);
                b0 += bflo(u0b.x) + bflo(u1b.x);
                b1 += bfhi(u0b.x) + bfhi(u1b.x);
                b2 += bflo(u0b.y) + bflo(u1b.y);
                b3 += bfhi(u0b.y) + bfhi(u1b.y);
                if (da) ja += 8;
                if (db) jb += 8;
            }
            a0 += __shfl(a0, lane ^ 16); a0 += __shfl(a0, lane ^ 32);
            a1 += __shfl(a1, lane ^ 16); a1 += __shfl(a1, lane ^ 32);
            a2 += __shfl(a2, lane ^ 16); a2 += __shfl(a2, lane ^ 32);
            a3 += __shfl(a3, lane ^ 16); a3 += __shfl(a3, lane ^ 32);
            b0 += __shfl(b0, lane ^ 16); b0 += __shfl(b0, lane ^ 32);
            b1 += __shfl(b1, lane ^ 16); b1 += __shfl(b1, lane ^ 32);
            b2 += __shfl(b2, lane ^ 16); b2 += __shfl(b2, lane ^ 32);
            b3 += __shfl(b3, lane ^ 16); b3 += __shfl(b3, lane ^ 32);
            if (q4 == 0) {   // lanes 0-15 hold cols c16*4 .. c16*4+3
                const unsigned int pa0 =
                    (unsigned int)f2bf(a0) | ((unsigned int)f2bf(a1) << 16);
                const unsigned int pa1 =
                    (unsigned int)f2bf(a2) | ((unsigned int)f2bf(a3) << 16);
                *(uint2*)(saggb + nA * 72 + c16 * 4) = make_uint2(pa0, pa1);
                const unsigned int pb0 =
                    (unsigned int)f2bf(b0) | ((unsigned int)f2bf(b1) << 16);
                const unsigned int pb1 =
                    (unsigned int)f2bf(b2) | ((unsigned int)f2bf(b3) << 16);
                *(uint2*)(saggb + nB * 72 + c16 * 4) = make_uint2(pb0, pb1);
            }
        }
    } else {
        // statistically-unreachable overflow: per-node scan of all runs
        __syncthreads();
        __syncthreads();
        for (int n = wv; n < PSZ; n += 8) {
            float acc = 0.f;
            for (int c = 0; c < nbs; ++c) {
                const unsigned short* ro = runoffC + (size_t)c * (np + 1);
                const int st = ro[p];
                const int en = ro[p + 1];
                const int* g = slab + (size_t)c * PSCH;
                for (int i = st; i < en; ++i) {
                    const int rec = g[i];
                    if (((rec >> 17) & 63) == n) {
                        const unsigned int us =
                            Fs16[((size_t)(rec & 0x1FFFF) << 6) + lane];
                        acc += __uint_as_float(us << 16);
                    }
                }
            }
            saggb[n * 72 + lane] = f2bf(acc);
        }
    }
    __syncthreads();

    // (d) 64x64x64 GEMM over 8 waves: wave wv -> m-tile wv>>1, n-tiles (wv&1)*2+{0,1}
    const int col = lane & 15;
    const int quad = lane >> 4;
    const int mt = wv >> 1;
    const int nh = (wv & 1) << 1;
    floatx4 acc[2] = {};
#pragma unroll
    for (int kt = 0; kt < 2; ++kt) {
        const short8 af = *(const short8*)(saggb + (mt * 16 + col) * 72 + kt * 32 + quad * 8);
#pragma unroll
        for (int t = 0; t < 2; ++t) {
            const int nt = nh + t;
            const short8 bf = *(const short8*)((const short*)WtB + (nt * 16 + col) * FEATS + kt * 32 + quad * 8);
            acc[t] = __builtin_amdgcn_mfma_f32_16x16x32_bf16(af, bf, acc[t], 0, 0, 0);
        }
    }
#pragma unroll
    for (int t = 0; t < 2; ++t) {
        const int nt = nh + t;
        const float bv = bias[nt * 16 + col];
#pragma unroll
        for (int r = 0; r < 4; ++r) {
            const int row = mt * 16 + quad * 4 + r;      // D: col=lane&15, row=quad*4+reg
            if (row < nn)
                out[(size_t)(n0 + row) * FEATS + nt * 16 + col] = swinv[row] * acc[t][r] + bv;
        }
    }
}

static inline size_t align256(size_t x) { return (x + 255) & ~(size_t)255; }

extern "C" void kernel_launch(void* const* d_in, const int* in_sizes, int n_in,
                              void* d_out, int out_size, void* d_ws, size_t ws_size,
                              hipStream_t stream) {
    const float* feature = (const float*)d_in[0];
    const float* degree  = (const float*)d_in[1];
    const int*   src     = (const int*)d_in[2];
    const int*   dst     = (const int*)d_in[3];
    const float* Wm      = (const float*)d_in[4];
    const float* bias    = (const float*)d_in[5];
    float* out = (float*)d_out;

    const int n_nodes = in_sizes[1];
    const int n_edges = in_sizes[2];
    const int np = (n_nodes + PSZ - 1) / PSZ;           // 1172
    const int nbs = NCH;                                // 256 sort chunks
    const int ncv = (n_nodes * 8 + SPTP - 1) / SPTP;    // 586 convert blocks

    // workspace (~15.3 MB), every byte read is rewritten each launch
    char* ws = (char*)d_ws;
    unsigned short* Fs16 = (unsigned short*)ws; ws += align256(((size_t)n_nodes + 1) * FEATS * 2);
    unsigned short* WtB  = (unsigned short*)ws; ws += align256((size_t)FEATS * FEATS * 2);
    int* slab = (int*)ws;                       ws += align256((size_t)NCH * PSCH * 4);
    unsigned short* runoffC = (unsigned short*)ws; ws += align256((size_t)NCH * (np + 1) * 2);

    prep_fused<<<nbs + ncv, SPTP, 0, stream>>>(degree, feature, Wm, src, dst,
                                               Fs16, WtB, slab, runoffC,
                                               n_nodes, n_edges, np, nbs);
    gather_apply16<<<np, SPT, 0, stream>>>(slab, runoffC, degree, Fs16, WtB, bias, out,
                                           n_nodes, np, nbs);
}

// Round 15
// 120.115 us; speedup vs baseline: 1.1736x; 1.0250x over previous
//
#include <hip/hip_runtime.h>

#define FEATS 64
#define PSZ   64            // nodes per partition (= one gather block)
#define MAXP  1280          // >= ceil(75000/64) = 1172
#define PSCH  4688          // edges per chunk; 4688*256 >= 1.2M
#define SPT   512           // gather threads per block
#define SPTP  1024          // prep threads per block (16 waves)
#define PEPT  5             // ceil(PSCH/SPTP)
#define NCH   256           // sort chunks
#define CAPP  2560          // padded LDS bucket capacity (mean ~1250 w/ pad8)

typedef __attribute__((ext_vector_type(8))) short short8;   // 8 bf16 = 4 VGPRs
typedef __attribute__((ext_vector_type(4))) float floatx4;  // MFMA accumulator

static __device__ __forceinline__ unsigned short f2bf(float f) {
    const unsigned int u = __float_as_uint(f);
    return (unsigned short)((u + 0x7FFFu + ((u >> 16) & 1u)) >> 16);
}
static __device__ __forceinline__ float bflo(unsigned int u) {
    return __uint_as_float(u << 16);            // low bf16 -> fp32
}
static __device__ __forceinline__ float bfhi(unsigned int u) {
    return __uint_as_float(u & 0xFFFF0000u);    // high bf16 -> fp32
}

// ---------------------------------------------------------------------------
// K1 prep_fused (R11 verbatim): heterogeneous grid, 1024-thread blocks.
//  blocks [0,nbs): SORT role. Preloaded dst -> LDS-atomic rank -> preloaded
//    src overlapping the 16-wave shuffle scan -> LDS placement -> coalesced
//    slab write + chunk-major runoffC[chunk][p] contiguous row write.
//  blocks [nbs,...): CONVERT role. Fs16 = bf16(feature*rsqrt(deg)).
// prk = p | r<<11 | dl<<24 (r < 4688: 13 bits). Record = src | dl<<17.
// ---------------------------------------------------------------------------
__global__ __launch_bounds__(SPTP) void prep_fused(
        const float* __restrict__ degree,
        const float* __restrict__ feature,
        const float* __restrict__ Wm,
        const int* __restrict__ src,
        const int* __restrict__ dst,
        unsigned short* __restrict__ Fs16,
        unsigned short* __restrict__ WtB,
        int* __restrict__ slab,
        unsigned short* __restrict__ runoffC,
        int n_nodes, int n_edges, int np, int nbs) {
    __shared__ int cnt[MAXP];        // per-partition count, then exclusive loc
    __shared__ int swt[16];          // per-wave scan totals
    __shared__ __align__(16) int sval[PSCH];
    const int tid = threadIdx.x;
    const int lane = tid & 63;
    const int wv = tid >> 6;
    const int b = blockIdx.x;

    if (b >= nbs) {
        // ---- CONVERT role: pure streaming, one 8-elem chunk per thread ----
        const int idx = (b - nbs) * SPTP + tid;
        const int total = n_nodes * 8;
        if (idx < total) {
            const float w = rsqrtf(degree[idx >> 3]);
            const float4* f4 = (const float4*)feature;
            const float4 fa = f4[idx * 2];
            const float4 fb = f4[idx * 2 + 1];
            uint4 o;
            o.x = (unsigned int)f2bf(fa.x * w) | ((unsigned int)f2bf(fa.y * w) << 16);
            o.y = (unsigned int)f2bf(fa.z * w) | ((unsigned int)f2bf(fa.w * w) << 16);
            o.z = (unsigned int)f2bf(fb.x * w) | ((unsigned int)f2bf(fb.y * w) << 16);
            o.w = (unsigned int)f2bf(fb.z * w) | ((unsigned int)f2bf(fb.w * w) << 16);
            ((uint4*)Fs16)[idx] = o;
        }
        if (b == nbs) {
            if (tid < FEATS) Fs16[(size_t)n_nodes * FEATS + tid] = 0;  // zero row
            for (int i = tid; i < FEATS * FEATS; i += SPTP) {
                const int k = i >> 6, n = i & 63;
                WtB[n * FEATS + k] = f2bf(Wm[i]);       // W^T in bf16
            }
        }
        return;
    }

    // ---- SORT role ----
    for (int i = tid; i < np; i += SPTP) cnt[i] = 0;
    __syncthreads();

    const int estart = b * PSCH;
    const int eend = min(estart + PSCH, n_edges);
    const int mb = eend - estart;

    int dv[PEPT];
#pragma unroll
    for (int k = 0; k < PEPT; ++k) {
        const int e = estart + tid + k * SPTP;
        dv[k] = (e < eend) ? dst[e] : -1;
    }
    int prk[PEPT];
#pragma unroll
    for (int k = 0; k < PEPT; ++k) {
        prk[k] = 0;
        if (dv[k] >= 0) {
            const int d = dv[k];
            const int p = d >> 6;                      // 11 bits
            const int r = atomicAdd(&cnt[p], 1);       // LDS atomic (native int)
            prk[k] = p | (r << 11) | ((d & 63) << 24); // r < 4688 (13 bits)
        }
    }
    int sv[PEPT];
#pragma unroll
    for (int k = 0; k < PEPT; ++k) {
        const int e = estart + tid + k * SPTP;
        sv[k] = (e < eend) ? src[e] : 0;
    }
    __syncthreads();

    // exclusive scan of cnt[0..np): 2/thread, wave shuffle + cross-wave
    int my[2];
    int psum = 0;
    const int p0 = tid * 2;
#pragma unroll
    for (int j = 0; j < 2; ++j) {
        const int p = p0 + j;
        my[j] = psum;
        if (p < np) psum += cnt[p];
    }
    int x = psum;
#pragma unroll
    for (int off = 1; off < 64; off <<= 1) {
        const int v = __shfl_up(x, off);
        if (lane >= off) x += v;
    }
    if (lane == 63) swt[wv] = x;
    __syncthreads();
    int wbase = 0;
#pragma unroll
    for (int w = 0; w < 16; ++w) if (w < wv) wbase += swt[w];
    const int tbase = wbase + (x - psum);
#pragma unroll
    for (int j = 0; j < 2; ++j) {
        const int p = p0 + j;
        if (p < np) cnt[p] = tbase + my[j];            // cnt becomes loc
    }
    __syncthreads();

#pragma unroll
    for (int k = 0; k < PEPT; ++k) {
        if (dv[k] >= 0) {
            const int pr = prk[k];
            const int p = pr & 2047;
            const int r = (pr >> 11) & 8191;
            const int dl = (pr >> 24) & 63;
            sval[cnt[p] + r] = (sv[k] & 0x1FFFF) | (dl << 17);
        }
    }
    __syncthreads();

    int* so = slab + estart;
    const int m4 = mb >> 2;                            // estart*4B is 16B-aligned
    int4* so4 = (int4*)so;
    const int4* sv4 = (const int4*)sval;
    for (int i = tid; i < m4; i += SPTP) so4[i] = sv4[i];
    for (int i = (m4 << 2) + tid; i < mb; i += SPTP) so[i] = sval[i];
    // chunk-major run-offset row: contiguous, coalesced, no cross-XCD sharing
    unsigned short* ro = runoffC + (size_t)b * (np + 1);
    for (int i = tid; i <= np; i += SPTP)
        ro[i] = (unsigned short)((i < np) ? cnt[i] : mb);
}

// ---------------------------------------------------------------------------
// K2 gather_apply17 (R14 + QUAD-node interleaved gather): block = partition
//  (XCD-chunk-swizzled), 512 threads.
//  (a) per-node 8-aligned bucket offsets (wave-0 shuffle scan),
//  (b) bucket from contiguous runoffC rows + 256 slab runs (4 thr/run),
//  (c) QUAD-NODE gather: each wave runs FOUR buckets' streams interleaved —
//      per step: 2 guarded loads per stream issued before any consume
//      => 8 independent line-fetches in flight at every step (R14 dual = 4,
//      +2.8 us; extend the proven concurrency mechanism). Wave-uniform conds.
//  (d) MFMA epilogue split across 8 waves: 1 m-tile x 2 n-tiles each.
// ---------------------------------------------------------------------------
__global__ __launch_bounds__(512, 8) void gather_apply17(
        const int* __restrict__ slab,
        const unsigned short* __restrict__ runoffC,
        const float* __restrict__ degree,
        const unsigned short* __restrict__ Fs16,
        const unsigned short* __restrict__ WtB,
        const float* __restrict__ bias,
        float* __restrict__ out,
        int n_nodes, int np, int nbs) {
    __shared__ __align__(16) int ledges[CAPP];                // 10 KB
    __shared__ __align__(16) unsigned short saggb[PSZ * 72];  // 9.2 KB bf16 A-tile
    __shared__ int boffA[PSZ + 1];
    __shared__ int bcur[PSZ];
    __shared__ float swinv[PSZ];

    const int tid = threadIdx.x;
    const int lane = tid & 63;
    const int wv = tid >> 6;

    // bijective XCD-chunked swizzle (8 XCDs): consecutive p on same XCD
    int p;
    {
        const int bid = blockIdx.x;
        const int q = np >> 3, r = np & 7;
        const int xcd = bid & 7, idx = bid >> 3;
        p = ((xcd < r) ? xcd * (q + 1) : r * (q + 1) + (xcd - r) * q) + idx;
    }
    const int n0 = p * PSZ;
    const int nn = min(PSZ, n_nodes - n0);

    if (tid < PSZ) bcur[tid] = 0;
    if (wv == 0) {   // wave-0: swinv + shuffle scan of 8-padded counts
        const float dg = (lane < nn) ? degree[n0 + lane] : 1.0f;
        swinv[lane] = rsqrtf(dg);
        const int c = (lane < nn) ? ((int)(dg + 0.5f) - 1) : 0;
        const int cp = (c + 7) & ~7;
        int x = cp;
#pragma unroll
        for (int off = 1; off < 64; off <<= 1) {
            const int v = __shfl_up(x, off);
            if (lane >= off) x += v;
        }
        if (lane == 0) boffA[0] = 0;
        boffA[lane + 1] = x;
    }
    __syncthreads();
    const int mpad = boffA[PSZ];

    if (mpad <= CAPP) {
        // (b) prefill pad slots with zero-row index, then bucket (4 thr/run)
        for (int i = tid; i < mpad; i += SPT) ledges[i] = n_nodes;
        __syncthreads();
        for (int t = tid; t < nbs * 4; t += SPT) {
            const int rr = t >> 2, sub = t & 3;
            const unsigned short* ro = runoffC + (size_t)rr * (np + 1);
            const int st = ro[p];
            const int en = ro[p + 1];
            const int* g = slab + (size_t)rr * PSCH;
            for (int q = st + sub; q < en; q += 4) {
                const int rec = g[q];
                const int dl = (rec >> 17) & 63;
                const int pos = boffA[dl] + atomicAdd(&bcur[dl], 1);
                if (pos < mpad) ledges[pos] = rec & 0x1FFFF;
            }
        }
        __syncthreads();

        // (c) quad-node interleaved gather
        const int q4 = lane >> 4;                  // quarter: edge within group
        const int c16 = lane & 15;                 // 4 cols per lane
        const uint2* FsU2 = (const uint2*)Fs16;    // 16 uint2 per 128B row
        for (int pr = wv; pr < 16; pr += 8) {
            const int nA = pr * 4;
            int ja = boffA[nA];     const int ea = boffA[nA + 1];
            int jb = boffA[nA + 1]; const int eb = boffA[nA + 2];
            int jc = boffA[nA + 2]; const int ec = boffA[nA + 3];
            int jd = boffA[nA + 3]; const int ed = boffA[nA + 4];
            float a0 = 0.f, a1 = 0.f, a2 = 0.f, a3 = 0.f;
            float b0 = 0.f, b1 = 0.f, b2 = 0.f, b3 = 0.f;
            float c0 = 0.f, c1 = 0.f, c2 = 0.f, c3 = 0.f;
            float d0 = 0.f, d1 = 0.f, d2 = 0.f, d3 = 0.f;
            while (ja < ea || jb < eb || jc < ec || jd < ed) {  // wave-uniform
                uint2 u0a = make_uint2(0u, 0u), u1a = make_uint2(0u, 0u);
                uint2 u0b = make_uint2(0u, 0u), u1b = make_uint2(0u, 0u);
                uint2 u0c = make_uint2(0u, 0u), u1c = make_uint2(0u, 0u);
                uint2 u0d = make_uint2(0u, 0u), u1d = make_uint2(0u, 0u);
                const bool da = ja < ea;
                const bool db = jb < eb;
                const bool dc = jc < ec;
                const bool dd = jd < ed;
                if (da) {                           // issue stream-A loads
                    const int r0 = ledges[ja + q4];
                    const int r1 = ledges[ja + 4 + q4];
                    u0a = FsU2[((size_t)r0 << 4) + c16];
                    u1a = FsU2[((size_t)r1 << 4) + c16];
                }
                if (db) {                           // issue stream-B loads
                    const int r0 = ledges[jb + q4];
                    const int r1 = ledges[jb + 4 + q4];
                    u0b = FsU2[((size_t)r0 << 4) + c16];
                    u1b = FsU2[((size_t)r1 << 4) + c16];
                }
                if (dc) {                           // issue stream-C loads
                    const int r0 = ledges[jc + q4];
                    const int r1 = ledges[jc + 4 + q4];
                    u0c = FsU2[((size_t)r0 << 4) + c16];
                    u1c = FsU2[((size_t)r1 << 4) + c16];
                }
                if (dd) {                           // issue stream-D loads
                    const int r0 = ledges[jd + q4];
                    const int r1 = ledges[jd + 4 + q4];
                    u0d = FsU2[((size_t)r0 << 4) + c16];
                    u1d = FsU2[((size_t)r1 << 4) + c16];
                }
                a0 += bflo(u0a.x) + bflo(u1a.x);
                a1 += bfhi(u0a.x) + bfhi(u1a.x);
                a2 += bflo(u0a.y) + bflo(u1a.y);
                a3 += bfhi(u0a.y) + bfhi(u1a.y);
                b0 += bflo(u0b.x) + bflo(u1b.x);
                b1 += bfhi(u0b.x) + bfhi(u1b.x);
                b2 += bflo(u0b.y) + bflo(u1b.y);
                b3 += bfhi(u0b.y) + bfhi(u1b.y);
                c0 += bflo(u0c.x) + bflo(u1c.x);
                c1 += bfhi(u0c.x) + bfhi(u1c.x);
                c2 += bflo(u0c.y) + bflo(u1c.y);
                c3 += bfhi(u0c.y) + bfhi(u1c.y);
                d0 += bflo(u0d.x) + bflo(u1d.x);
                d1 += bfhi(u0d.x) + bfhi(u1d.x);
                d2 += bflo(u0d.y) + bflo(u1d.y);
                d3 += bfhi(u0d.y) + bfhi(u1d.y);
                if (da) ja += 8;
                if (db) jb += 8;
                if (dc) jc += 8;
                if (dd) jd += 8;
            }
#define FOLD(v) v += __shfl(v, lane ^ 16); v += __shfl(v, lane ^ 32)
            FOLD(a0); FOLD(a1); FOLD(a2); FOLD(a3);
            FOLD(b0); FOLD(b1); FOLD(b2); FOLD(b3);
            FOLD(c0); FOLD(c1); FOLD(c2); FOLD(c3);
            FOLD(d0); FOLD(d1); FOLD(d2); FOLD(d3);
#undef FOLD
            if (q4 == 0) {   // lanes 0-15 hold cols c16*4 .. c16*4+3
                *(uint2*)(saggb + (nA + 0) * 72 + c16 * 4) = make_uint2(
                    (unsigned int)f2bf(a0) | ((unsigned int)f2bf(a1) << 16),
                    (unsigned int)f2bf(a2) | ((unsigned int)f2bf(a3) << 16));
                *(uint2*)(saggb + (nA + 1) * 72 + c16 * 4) = make_uint2(
                    (unsigned int)f2bf(b0) | ((unsigned int)f2bf(b1) << 16),
                    (unsigned int)f2bf(b2) | ((unsigned int)f2bf(b3) << 16));
                *(uint2*)(saggb + (nA + 2) * 72 + c16 * 4) = make_uint2(
                    (unsigned int)f2bf(c0) | ((unsigned int)f2bf(c1) << 16),
                    (unsigned int)f2bf(c2) | ((unsigned int)f2bf(c3) << 16));
                *(uint2*)(saggb + (nA + 3) * 72 + c16 * 4) = make_uint2(
                    (unsigned int)f2bf(d0) | ((unsigned int)f2bf(d1) << 16),
                    (unsigned int)f2bf(d2) | ((unsigned int)f2bf(d3) << 16));
            }
        }
    } else {
        // statistically-unreachable overflow: per-node scan of all runs
        __syncthreads();
        __syncthreads();
        for (int n = wv; n < PSZ; n += 8) {
            float acc = 0.f;
            for (int c = 0; c < nbs; ++c) {
                const unsigned short* ro = runoffC + (size_t)c * (np + 1);
                const int st = ro[p];
                const int en = ro[p + 1];
                const int* g = slab + (size_t)c * PSCH;
                for (int i = st; i < en; ++i) {
                    const int rec = g[i];
                    if (((rec >> 17) & 63) == n) {
                        const unsigned int us =
                            Fs16[((size_t)(rec & 0x1FFFF) << 6) + lane];
                        acc += __uint_as_float(us << 16);
                    }
                }
            }
            saggb[n * 72 + lane] = f2bf(acc);
        }
    }
    __syncthreads();

    // (d) 64x64x64 GEMM over 8 waves: wave wv -> m-tile wv>>1, n-tiles (wv&1)*2+{0,1}
    const int col = lane & 15;
    const int quad = lane >> 4;
    const int mt = wv >> 1;
    const int nh = (wv & 1) << 1;
    floatx4 acc[2] = {};
#pragma unroll
    for (int kt = 0; kt < 2; ++kt) {
        const short8 af = *(const short8*)(saggb + (mt * 16 + col) * 72 + kt * 32 + quad * 8);
#pragma unroll
        for (int t = 0; t < 2; ++t) {
            const int nt = nh + t;
            const short8 bf = *(const short8*)((const short*)WtB + (nt * 16 + col) * FEATS + kt * 32 + quad * 8);
            acc[t] = __builtin_amdgcn_mfma_f32_16x16x32_bf16(af, bf, acc[t], 0, 0, 0);
        }
    }
#pragma unroll
    for (int t = 0; t < 2; ++t) {
        const int nt = nh + t;
        const float bv = bias[nt * 16 + col];
#pragma unroll
        for (int r = 0; r < 4; ++r) {
            const int row = mt * 16 + quad * 4 + r;      // D: col=lane&15, row=quad*4+reg
            if (row < nn)
                out[(size_t)(n0 + row) * FEATS + nt * 16 + col] = swinv[row] * acc[t][r] + bv;
        }
    }
}

static inline size_t align256(size_t x) { return (x + 255) & ~(size_t)255; }

extern "C" void kernel_launch(void* const* d_in, const int* in_sizes, int n_in,
                              void* d_out, int out_size, void* d_ws, size_t ws_size,
                              hipStream_t stream) {
    const float* feature = (const float*)d_in[0];
    const float* degree  = (const float*)d_in[1];
    const int*   src     = (const int*)d_in[2];
    const int*   dst     = (const int*)d_in[3];
    const float* Wm      = (const float*)d_in[4];
    const float* bias    = (const float*)d_in[5];
    float* out = (float*)d_out;

    const int n_nodes = in_sizes[1];
    const int n_edges = in_sizes[2];
    const int np = (n_nodes + PSZ - 1) / PSZ;           // 1172
    const int nbs = NCH;                                // 256 sort chunks
    const int ncv = (n_nodes * 8 + SPTP - 1) / SPTP;    // 586 convert blocks

    // workspace (~15.3 MB), every byte read is rewritten each launch
    char* ws = (char*)d_ws;
    unsigned short* Fs16 = (unsigned short*)ws; ws += align256(((size_t)n_nodes + 1) * FEATS * 2);
    unsigned short* WtB  = (unsigned short*)ws; ws += align256((size_t)FEATS * FEATS * 2);
    int* slab = (int*)ws;                       ws += align256((size_t)NCH * PSCH * 4);
    unsigned short* runoffC = (unsigned short*)ws; ws += align256((size_t)NCH * (np + 1) * 2);

    prep_fused<<<nbs + ncv, SPTP, 0, stream>>>(degree, feature, Wm, src, dst,
                                               Fs16, WtB, slab, runoffC,
                                               n_nodes, n_edges, np, nbs);
    gather_apply17<<<np, SPT, 0, stream>>>(slab, runoffC, degree, Fs16, WtB, bias, out,
                                           n_nodes, np, nbs);
}